// Round 5
// baseline (686.105 us; speedup 1.0000x reference)
//
#include <hip/hip_runtime.h>
#include <hip/hip_bf16.h>

typedef __attribute__((ext_vector_type(8))) short bhalf8;
typedef __attribute__((ext_vector_type(4))) short bhalf4;
typedef __attribute__((ext_vector_type(4))) float f32x4;
typedef __attribute__((ext_vector_type(16))) float f32x16;
typedef __attribute__((ext_vector_type(4))) unsigned int u32x4;

#define S_SEQ 4096
#define DMODEL 2048
#define NHEAD 16
#define DHEAD 128

__device__ __forceinline__ short f2bf(float f) {
  union { float f; unsigned int u; } v; v.f = f;
  unsigned int r = v.u + 0x7fffu + ((v.u >> 16) & 1u);
  return (short)(r >> 16);
}
__device__ __forceinline__ float bf2f(short s) {
  union { unsigned int u; float f; } v; v.u = ((unsigned int)(unsigned short)s) << 16;
  return v.f;
}
__device__ __forceinline__ unsigned pk2(float a, float b) {
  union { __hip_bfloat16 h; unsigned short u; } x, y;
  x.h = __float2bfloat16(a); y.h = __float2bfloat16(b);
  return (unsigned)x.u | ((unsigned)y.u << 16);
}

// ---------------- elementwise f32 -> bf16 ----------------
__global__ __launch_bounds__(256) void k_convert(const float* __restrict__ in,
                                                 short* __restrict__ out, int n4) {
  int i = blockIdx.x * 256 + threadIdx.x;
  if (i >= n4) return;
  f32x4 v = ((const f32x4*)in)[i];
  bhalf4 o;
  o[0] = f2bf(v[0]); o[1] = f2bf(v[1]); o[2] = f2bf(v[2]); o[3] = f2bf(v[3]);
  ((bhalf4*)out)[i] = o;
}

// ------- batched transpose+convert: in [B][R][C] f32 -> out [B][C][R] bf16 -------
__global__ __launch_bounds__(256) void k_transpose(const float* __restrict__ in,
                                                   short* __restrict__ out, int R, int C) {
  long bs = (long)R * C;
  const float* inp = in + (long)blockIdx.y * bs;
  short* outp = out + (long)blockIdx.y * bs;
  int ct = C >> 6;
  int r0 = (blockIdx.x / ct) << 6;
  int c0 = (blockIdx.x % ct) << 6;
  __shared__ float T[64][65];
  int tid = threadIdx.x;
#pragma unroll
  for (int i = 0; i < 4; i++) {
    int chunk = tid + i * 256;
    int r = chunk >> 4, c = (chunk & 15) << 2;
    f32x4 v = *(const f32x4*)(inp + (long)(r0 + r) * C + c0 + c);
    T[r][c] = v[0]; T[r][c + 1] = v[1]; T[r][c + 2] = v[2]; T[r][c + 3] = v[3];
  }
  __syncthreads();
#pragma unroll
  for (int i = 0; i < 4; i++) {
    int chunk = tid + i * 256;
    int oc = chunk >> 4, o4 = (chunk & 15) << 2;
    bhalf4 o;
    o[0] = f2bf(T[o4][oc]);     o[1] = f2bf(T[o4 + 1][oc]);
    o[2] = f2bf(T[o4 + 2][oc]); o[3] = f2bf(T[o4 + 3][oc]);
    *(bhalf4*)(outp + (long)(c0 + oc) * R + r0 + o4) = o;
  }
}

// ---------------- GEMM: C[m][n] = alpha*(A[m][:] . Bt[n][:] + bias) ----------------
// MODE 0: C bf16, bias per col. MODE 1: C bf16, bias per row. MODE 2: C f32, bias per col.
template <int MODE>
__global__ __launch_bounds__(256) void k_gemm(const short* __restrict__ A, int lda, long a_bs,
                                              const short* __restrict__ Bt, int ldb, long b_bs,
                                              void* __restrict__ Cp, int ldc, long c_bs,
                                              const float* __restrict__ bias, int bias_bs,
                                              float alpha,
                                              int Mtiles, int Ntiles, int K) {
  const int b = blockIdx.y;
  A += (long)b * a_bs;
  Bt += (long)b * b_bs;
  bias += (long)b * bias_bs;
  const int bx = blockIdx.x;
  const int mt = bx / Ntiles, nt = bx % Ntiles;
  const int row0 = mt << 7, col0 = nt << 7;
  const int tid = threadIdx.x;
  const int wave = tid >> 6, lane = tid & 63;
  const int wr = wave >> 1, wc = wave & 1;
  const int lr = lane & 15, lg = lane >> 4;

  __shared__ short As[128][72];
  __shared__ short Bs[128][72];

  f32x4 acc[4][4];
#pragma unroll
  for (int mi = 0; mi < 4; mi++)
#pragma unroll
    for (int ni = 0; ni < 4; ni++) acc[mi][ni] = (f32x4){0.f, 0.f, 0.f, 0.f};

  for (int k0 = 0; k0 < K; k0 += 64) {
    __syncthreads();
#pragma unroll
    for (int i = 0; i < 4; i++) {
      int chunk = tid + i * 256;
      int r = chunk >> 3, c = (chunk & 7) << 3;
      *(bhalf8*)&As[r][c] = *(const bhalf8*)(A + (long)(row0 + r) * lda + k0 + c);
      *(bhalf8*)&Bs[r][c] = *(const bhalf8*)(Bt + (long)(col0 + r) * ldb + k0 + c);
    }
    __syncthreads();
#pragma unroll
    for (int kk = 0; kk < 2; kk++) {
      bhalf8 af[4], bf[4];
#pragma unroll
      for (int mi = 0; mi < 4; mi++)
        af[mi] = *(const bhalf8*)&As[wr * 64 + mi * 16 + lr][kk * 32 + lg * 8];
#pragma unroll
      for (int ni = 0; ni < 4; ni++)
        bf[ni] = *(const bhalf8*)&Bs[wc * 64 + ni * 16 + lr][kk * 32 + lg * 8];
#pragma unroll
      for (int mi = 0; mi < 4; mi++)
#pragma unroll
        for (int ni = 0; ni < 4; ni++)
          acc[mi][ni] = __builtin_amdgcn_mfma_f32_16x16x32_bf16(af[mi], bf[ni], acc[mi][ni], 0, 0, 0);
    }
  }

#pragma unroll
  for (int mi = 0; mi < 4; mi++) {
#pragma unroll
    for (int ni = 0; ni < 4; ni++) {
#pragma unroll
      for (int r = 0; r < 4; r++) {
        int row = row0 + wr * 64 + mi * 16 + lg * 4 + r;
        int col = col0 + wc * 64 + ni * 16 + lr;
        float v = acc[mi][ni][r];
        if (MODE == 0) {
          v = (v + bias[col]) * alpha;
          ((short*)Cp)[(long)b * c_bs + (long)row * ldc + col] = f2bf(v);
        } else if (MODE == 1) {
          v = (v + bias[row]) * alpha;
          ((short*)Cp)[(long)b * c_bs + (long)row * ldc + col] = f2bf(v);
        } else {
          v += bias[col];
          ((float*)Cp)[(long)b * c_bs + (long)row * ldc + col] = v;
        }
      }
    }
  }
}

// ---------------- flash attention, split-KV x2, KVBLK=32, 32KB LDS ----------------
// grid: 1024 blocks = (16 heads x 32 q-tiles x 2 kv-halves) via XCD swizzle, 256 thr.
// Each wave owns 32 q rows; each lane owns ONE q row (q = l&31; lanes l, l+32 pair).
// Partial output (raw accO, m, l) per block -> Opart/ml; k_merge combines halves.
__global__ __launch_bounds__(256, 4) void k_attn(const short* __restrict__ q,
                                                 const short* __restrict__ k,
                                                 const short* __restrict__ vT,
                                                 short* __restrict__ Opart,
                                                 float* __restrict__ mlbuf) {
  __shared__ __align__(16) char smem[32768]; // 2 x (K 8KB + V^T 8KB), XOR-swizzled
  const int wg = blockIdx.x;
  const int wgid = (wg & 7) * 128 + (wg >> 3);  // XCD swizzle: 2 heads per XCD
  const int h = wgid >> 6;
  const int qt = (wgid & 63) >> 1;
  const int half = wgid & 1;
  const int q0 = qt << 7;
  const int kvbase = half << 11;                // 0 or 2048
  const int tid = threadIdx.x;
  const int wave = tid >> 6;
  const int l31 = tid & 31;
  const int hi = (tid >> 5) & 1;
  const int swl = (tid & 15) << 4;              // XOR key for this lane's frag rows

  const long qk_base = (long)h * S_SEQ * DHEAD;
  const long vt_base = (long)h * DHEAD * S_SEQ;

  // ---- stage Q tile (128 rows x 256B = 32KB) through LDS, swizzled ----
  {
    u32x4 qst[8];
#pragma unroll
    for (int rnd = 0; rnd < 8; rnd++) {
      int o = rnd * 4096 + tid * 16;
      int row = o >> 8, col = o & 255;
      qst[rnd] = *(const u32x4*)(q + qk_base + (long)(q0 + row) * DHEAD + (col >> 1));
    }
#pragma unroll
    for (int rnd = 0; rnd < 8; rnd++) {
      int o = rnd * 4096 + tid * 16;
      int row = o >> 8, col = o & 255;
      *(u32x4*)(smem + row * 256 + (col ^ ((row & 15) << 4))) = qst[rnd];
    }
  }
  __syncthreads();
  bhalf8 qf[8]; // B-frag: Q[q=l31][dk = kc*16 + hi*8 + j]
#pragma unroll
  for (int kc = 0; kc < 8; kc++) {
    int row = wave * 32 + l31;
    qf[kc] = *(const bhalf8*)(smem + row * 256 + ((kc * 32 + hi * 16) ^ swl));
  }
  __syncthreads();

  f32x16 accO[4];
#pragma unroll
  for (int d = 0; d < 4; d++)
#pragma unroll
    for (int r = 0; r < 16; r++) accO[d][r] = 0.f;
  float m_run = -1e30f, l_part = 0.f;

  u32x4 st[4];
  // staging: K tile 8KB (32 rows x 256B), V^T folded 8KB (32 rows x 256B; 4 dv/row)
  auto load_tile = [&](int kv0) {
#pragma unroll
    for (int rnd = 0; rnd < 2; rnd++) {
      int o = rnd * 4096 + tid * 16;
      int row = o >> 8, col = o & 255;
      st[rnd] = *(const u32x4*)(k + qk_base + (long)(kv0 + row) * DHEAD + (col >> 1));
    }
#pragma unroll
    for (int rnd = 0; rnd < 2; rnd++) {
      int o = rnd * 4096 + tid * 16;
      int dv = o >> 6, col = o & 63;
      st[2 + rnd] = *(const u32x4*)(vT + vt_base + (long)dv * S_SEQ + kv0 + (col >> 1));
    }
  };
  auto write_tile = [&](char* buf) {
#pragma unroll
    for (int rnd = 0; rnd < 2; rnd++) {
      int o = rnd * 4096 + tid * 16;
      int row = o >> 8, col = o & 255;
      *(u32x4*)(buf + row * 256 + (col ^ ((row & 15) << 4))) = st[rnd];
    }
#pragma unroll
    for (int rnd = 0; rnd < 2; rnd++) {
      int o = rnd * 4096 + tid * 16;
      int dv = o >> 6, col = o & 63;
      // folded: LDS row = dv&31, segment = (dv>>5)*64, key (dv&15)<<4
      *(u32x4*)(buf + 8192 + (dv & 31) * 256 +
                ((((dv >> 5) << 6) | col) ^ ((dv & 15) << 4))) = st[2 + rnd];
    }
  };

  load_tile(kvbase);
  write_tile(smem);
  load_tile(kvbase + 32);
  __syncthreads();

  const int NT = 2048 / 32; // 64 tiles per half
  for (int t = 0; t < NT; t++) {
    char* buf = smem + (t & 1) * 16384;

    // ---- QK^T: S^T[kv][q], kv = A-rows, q = lane ----
    f32x16 accS;
#pragma unroll
    for (int r = 0; r < 16; r++) accS[r] = 0.f;

    __builtin_amdgcn_s_setprio(1);
#pragma unroll
    for (int kc = 0; kc < 8; kc++) {
      bhalf8 kf = *(const bhalf8*)(buf + l31 * 256 + ((kc * 32 + hi * 16) ^ swl));
      accS = __builtin_amdgcn_mfma_f32_32x32x16_bf16(kf, qf[kc], accS, 0, 0, 0);
    }
    __builtin_amdgcn_s_setprio(0);

    // ---- online softmax (per-lane row; pair lane l^32 holds the other 16 kv) ----
    float mx[4];
#pragma unroll
    for (int g = 0; g < 4; g++) {
      int b4 = g * 4;
      mx[g] = fmaxf(fmaxf(accS[b4], accS[b4 + 1]), fmaxf(accS[b4 + 2], accS[b4 + 3]));
    }
    float mc = fmaxf(fmaxf(mx[0], mx[1]), fmaxf(mx[2], mx[3]));
    mc = fmaxf(mc, __shfl_xor(mc, 32));

    if (!__all(mc <= m_run + 8.f)) {   // defer-max: rescale only on real growth
      float mn = fmaxf(m_run, mc);
      float corr = __builtin_amdgcn_exp2f(m_run - mn);
      m_run = mn;
      l_part *= corr;
#pragma unroll
      for (int d = 0; d < 4; d++)
#pragma unroll
        for (int r = 0; r < 16; r++) accO[d][r] *= corr;
    }

    unsigned pk[4][2];
#pragma unroll
    for (int g = 0; g < 4; g++) {
      float p0 = __builtin_amdgcn_exp2f(accS[4 * g + 0] - m_run);
      float p1 = __builtin_amdgcn_exp2f(accS[4 * g + 1] - m_run);
      float p2 = __builtin_amdgcn_exp2f(accS[4 * g + 2] - m_run);
      float p3 = __builtin_amdgcn_exp2f(accS[4 * g + 3] - m_run);
      l_part += (p0 + p1) + (p2 + p3);
      pk[g][0] = pk2(p0, p1);
      pk[g][1] = pk2(p2, p3);
    }

    // ---- assemble PV B-operand in registers (xor-32 half exchange) ----
    bhalf8 pa[2]; // chunk c: P[q=l31][kv = 16c + 8hi + j]
#pragma unroll
    for (int c1 = 0; c1 < 2; c1++) {
      unsigned a0 = pk[2 * c1][0],     a1 = pk[2 * c1][1];
      unsigned b0 = pk[2 * c1 + 1][0], b1 = pk[2 * c1 + 1][1];
      unsigned s0a = (unsigned)__shfl_xor((int)a0, 32);
      unsigned s1a = (unsigned)__shfl_xor((int)a1, 32);
      unsigned s0b = (unsigned)__shfl_xor((int)b0, 32);
      unsigned s1b = (unsigned)__shfl_xor((int)b1, 32);
      union { unsigned u[4]; bhalf8 v; } cvt;
      cvt.u[0] = hi ? s0b : a0;
      cvt.u[1] = hi ? s1b : a1;
      cvt.u[2] = hi ? b0 : s0a;
      cvt.u[3] = hi ? b1 : s1a;
      pa[c1] = cvt.v;
    }

    // ---- PV: O^T[dv][q] += V^T[dv][kv] . P^T[kv][q] ----
    __builtin_amdgcn_s_setprio(1);
#pragma unroll
    for (int d = 0; d < 4; d++) {
#pragma unroll
      for (int c = 0; c < 2; c++) {
        bhalf8 vf = *(const bhalf8*)(buf + 8192 + l31 * 256 +
                                     (((d << 6) | (c * 32 + hi * 16)) ^ swl));
        accO[d] = __builtin_amdgcn_mfma_f32_32x32x16_bf16(vf, pa[c], accO[d], 0, 0, 0);
      }
    }
    __builtin_amdgcn_s_setprio(0);

    if (t + 1 < NT) write_tile(smem + ((t + 1) & 1) * 16384); // compiler waits vmcnt
    __syncthreads();
    if (t + 2 < NT) load_tile(kvbase + (t + 2) * 32);         // async issue
  }

  // ---- epilogue: raw partial (no normalization) ----
  float l_tot = l_part + __shfl_xor(l_part, 32);
  const int pidx = wgid; // h*64 + qt*2 + half
  const int qloc = wave * 32 + l31;
  long obase = (long)pidx * 16384 + (long)qloc * 128;
#pragma unroll
  for (int d = 0; d < 4; d++)
#pragma unroll
    for (int rg = 0; rg < 4; rg++) {
      bhalf4 ov;
#pragma unroll
      for (int i = 0; i < 4; i++) ov[i] = f2bf(accO[d][rg * 4 + i]);
      *(bhalf4*)(Opart + obase + d * 32 + rg * 8 + hi * 4) = ov;
    }
  if (hi == 0) {
    mlbuf[(long)pidx * 256 + qloc] = m_run;
    mlbuf[(long)pidx * 256 + 128 + qloc] = l_tot;
  }
}

// ---------------- merge the two KV halves ----------------
// grid 512 = (16 heads x 32 q-tiles), 256 thr.
__global__ __launch_bounds__(256) void k_merge(const short* __restrict__ Opart,
                                               const float* __restrict__ mlbuf,
                                               short* __restrict__ cat) {
  const int b = blockIdx.x;
  const int h = b >> 5, qt = b & 31;
  const int p0 = h * 64 + qt * 2;
  __shared__ float w1[128], w2[128];
  const int t = threadIdx.x;
  if (t < 128) {
    float m1 = mlbuf[(long)p0 * 256 + t];
    float l1 = mlbuf[(long)p0 * 256 + 128 + t];
    float m2 = mlbuf[(long)(p0 + 1) * 256 + t];
    float l2 = mlbuf[(long)(p0 + 1) * 256 + 128 + t];
    float m = fmaxf(m1, m2);
    float e1 = __builtin_amdgcn_exp2f(m1 - m);
    float e2 = __builtin_amdgcn_exp2f(m2 - m);
    float inv = 1.f / (e1 * l1 + e2 * l2);
    w1[t] = e1 * inv;
    w2[t] = e2 * inv;
  }
  __syncthreads();
  const int qq = t >> 1, d0 = (t & 1) * 64;
  const short* o1 = Opart + (long)p0 * 16384 + (long)qq * 128 + d0;
  const short* o2 = o1 + 16384;
  short* dst = cat + (long)(qt * 128 + qq) * DMODEL + h * DHEAD + d0;
  const float a = w1[qq], c = w2[qq];
#pragma unroll
  for (int i = 0; i < 8; i++) {
    bhalf8 x = *(const bhalf8*)(o1 + i * 8);
    bhalf8 y = *(const bhalf8*)(o2 + i * 8);
    bhalf8 o;
#pragma unroll
    for (int j = 0; j < 8; j++) o[j] = f2bf(bf2f(x[j]) * a + bf2f(y[j]) * c);
    *(bhalf8*)(dst + i * 8) = o;
  }
}

// ---------------- launch ----------------
extern "C" void kernel_launch(void* const* d_in, const int* in_sizes, int n_in,
                              void* d_out, int out_size, void* d_ws, size_t ws_size,
                              hipStream_t stream) {
  const float* x  = (const float*)d_in[0];
  const float* Wq = (const float*)d_in[1];
  const float* bq = (const float*)d_in[2];
  const float* Wk = (const float*)d_in[3];
  const float* bk = (const float*)d_in[4];
  const float* Wv = (const float*)d_in[5];
  const float* bv = (const float*)d_in[6];
  const float* Wo = (const float*)d_in[7];
  const float* bo = (const float*)d_in[8];
  float* out = (float*)d_out;

  short* x_bf   = (short*)d_ws;                        // [4096][2048]
  short* Wqt    = x_bf  + (long)S_SEQ * DMODEL;        // [16][128][2048]
  short* Wkt    = Wqt   + (long)NHEAD * DHEAD * DMODEL;
  short* Wvt    = Wkt   + (long)NHEAD * DHEAD * DMODEL;
  short* Wot    = Wvt   + (long)NHEAD * DHEAD * DMODEL; // [2048][2048]
  short* q_bf   = Wot   + (long)DMODEL * DMODEL;        // [16][4096][128]
  short* k_bf   = q_bf  + (long)NHEAD * S_SEQ * DHEAD;
  short* vT_bf  = k_bf  + (long)NHEAD * S_SEQ * DHEAD;  // [16][128][4096]
  short* cat_bf = vT_bf + (long)NHEAD * DHEAD * S_SEQ;  // [4096][2048]

  // attention partials ALIAS x_bf/Wqt/Wkt/Wvt (20.97M shorts): dead after projections.
  // Opart: 1024*16384 shorts (16.78M) + ml: 1024*256 f32 (0.52M shorts) = 17.3M. Fits.
  short* Opart  = x_bf;
  float* mlbuf  = (float*)(Opart + (long)1024 * 16384);

  dim3 blk(256);

  k_convert<<<dim3((S_SEQ * DMODEL / 4 + 255) / 256), blk, 0, stream>>>(x, x_bf, S_SEQ * DMODEL / 4);

  k_transpose<<<dim3((DMODEL / 64) * (DHEAD / 64), NHEAD), blk, 0, stream>>>(Wq, Wqt, DMODEL, DHEAD);
  k_transpose<<<dim3((DMODEL / 64) * (DHEAD / 64), NHEAD), blk, 0, stream>>>(Wk, Wkt, DMODEL, DHEAD);
  k_transpose<<<dim3((DMODEL / 64) * (DHEAD / 64), NHEAD), blk, 0, stream>>>(Wv, Wvt, DMODEL, DHEAD);
  k_transpose<<<dim3((DMODEL / 64) * (DMODEL / 64), 1), blk, 0, stream>>>(Wo, Wot, DMODEL, DMODEL);

  // scale*log2(e) folded into q so softmax exp is a single v_exp_f32 (base-2)
  const float alpha_q = 0.08838834764831845f * 1.4426950408889634f;

  k_gemm<0><<<dim3(32, NHEAD), blk, 0, stream>>>(x_bf, DMODEL, 0L,
                                                 Wqt, DMODEL, (long)DHEAD * DMODEL,
                                                 q_bf, DHEAD, (long)S_SEQ * DHEAD,
                                                 bq, DHEAD, alpha_q, 32, 1, DMODEL);
  k_gemm<0><<<dim3(32, NHEAD), blk, 0, stream>>>(x_bf, DMODEL, 0L,
                                                 Wkt, DMODEL, (long)DHEAD * DMODEL,
                                                 k_bf, DHEAD, (long)S_SEQ * DHEAD,
                                                 bk, DHEAD, 1.0f, 32, 1, DMODEL);
  // vT[h] = Wv[h]^T @ x^T + bv[h] (bias per row) : [128][4096] per head
  k_gemm<1><<<dim3(32, NHEAD), blk, 0, stream>>>(Wvt, DMODEL, (long)DHEAD * DMODEL,
                                                 x_bf, DMODEL, 0L,
                                                 vT_bf, S_SEQ, (long)DHEAD * S_SEQ,
                                                 bv, DHEAD, 1.0f, 1, 32, DMODEL);

  k_attn<<<dim3(1024), blk, 0, stream>>>(q_bf, k_bf, vT_bf, Opart, mlbuf);
  k_merge<<<dim3(512), blk, 0, stream>>>(Opart, mlbuf, cat_bf);

  // out = cat @ Wo + bo : [4096][2048] f32
  k_gemm<2><<<dim3(32 * 16, 1), blk, 0, stream>>>(cat_bf, DMODEL, 0L,
                                                  Wot, DMODEL, 0L,
                                                  out, DMODEL, 0L,
                                                  bo, 0, 1.0f, 32, 16, DMODEL);
}

// Round 7
// 356.568 us; speedup vs baseline: 1.9242x; 1.9242x over previous
//
#include <hip/hip_runtime.h>
#include <hip/hip_bf16.h>

typedef __attribute__((ext_vector_type(8))) short bhalf8;
typedef __attribute__((ext_vector_type(4))) short bhalf4;
typedef __attribute__((ext_vector_type(4))) float f32x4;
typedef __attribute__((ext_vector_type(16))) float f32x16;
typedef __attribute__((ext_vector_type(4))) unsigned int u32x4;

#define S_SEQ 4096
#define DMODEL 2048
#define NHEAD 16
#define DHEAD 128

__device__ __forceinline__ short f2bf(float f) {
  union { float f; unsigned int u; } v; v.f = f;
  unsigned int r = v.u + 0x7fffu + ((v.u >> 16) & 1u);
  return (short)(r >> 16);
}

__device__ __forceinline__ unsigned pk2(float a, float b) {
  union { __hip_bfloat16 h; unsigned short u; } x, y;
  x.h = __float2bfloat16(a); y.h = __float2bfloat16(b);
  return (unsigned)x.u | ((unsigned)y.u << 16);
}

// ---------------- elementwise f32 -> bf16 ----------------
__global__ __launch_bounds__(256) void k_convert(const float* __restrict__ in,
                                                 short* __restrict__ out, int n4) {
  int i = blockIdx.x * 256 + threadIdx.x;
  if (i >= n4) return;
  f32x4 v = ((const f32x4*)in)[i];
  bhalf4 o;
  o[0] = f2bf(v[0]); o[1] = f2bf(v[1]); o[2] = f2bf(v[2]); o[3] = f2bf(v[3]);
  ((bhalf4*)out)[i] = o;
}

// ------- batched transpose+convert: in [B][R][C] f32 -> out [B][C][R] bf16 -------
__global__ __launch_bounds__(256) void k_transpose(const float* __restrict__ in,
                                                   short* __restrict__ out, int R, int C) {
  long bs = (long)R * C;
  const float* inp = in + (long)blockIdx.y * bs;
  short* outp = out + (long)blockIdx.y * bs;
  int ct = C >> 6;
  int r0 = (blockIdx.x / ct) << 6;
  int c0 = (blockIdx.x % ct) << 6;
  __shared__ float T[64][65];
  int tid = threadIdx.x;
#pragma unroll
  for (int i = 0; i < 4; i++) {
    int chunk = tid + i * 256;
    int r = chunk >> 4, c = (chunk & 15) << 2;
    f32x4 v = *(const f32x4*)(inp + (long)(r0 + r) * C + c0 + c);
    T[r][c] = v[0]; T[r][c + 1] = v[1]; T[r][c + 2] = v[2]; T[r][c + 3] = v[3];
  }
  __syncthreads();
#pragma unroll
  for (int i = 0; i < 4; i++) {
    int chunk = tid + i * 256;
    int oc = chunk >> 4, o4 = (chunk & 15) << 2;
    bhalf4 o;
    o[0] = f2bf(T[o4][oc]);     o[1] = f2bf(T[o4 + 1][oc]);
    o[2] = f2bf(T[o4 + 2][oc]); o[3] = f2bf(T[o4 + 3][oc]);
    *(bhalf4*)(outp + (long)(c0 + oc) * R + r0 + o4) = o;
  }
}

// ---------------- GEMM: C[m][n] = alpha*(A[m][:] . Bt[n][:] + bias) ----------------
// MODE 0: C bf16, bias per col. MODE 1: C bf16, bias per row. MODE 2: C f32, bias per col.
template <int MODE>
__global__ __launch_bounds__(256) void k_gemm(const short* __restrict__ A, int lda, long a_bs,
                                              const short* __restrict__ Bt, int ldb, long b_bs,
                                              void* __restrict__ Cp, int ldc, long c_bs,
                                              const float* __restrict__ bias, int bias_bs,
                                              float alpha,
                                              int Mtiles, int Ntiles, int K) {
  const int b = blockIdx.y;
  A += (long)b * a_bs;
  Bt += (long)b * b_bs;
  bias += (long)b * bias_bs;
  int bx = blockIdx.x;
  // XCD-aware bijective swizzle for large 1-D grids (out-proj: 512 % 8 == 0)
  if (gridDim.y == 1) bx = (bx & 7) * (gridDim.x >> 3) + (bx >> 3);
  const int mt = bx / Ntiles, nt = bx % Ntiles;
  const int row0 = mt << 7, col0 = nt << 7;
  const int tid = threadIdx.x;
  const int wave = tid >> 6, lane = tid & 63;
  const int wr = wave >> 1, wc = wave & 1;
  const int lr = lane & 15, lg = lane >> 4;

  __shared__ short As[128][72];
  __shared__ short Bs[128][72];

  f32x4 acc[4][4];
#pragma unroll
  for (int mi = 0; mi < 4; mi++)
#pragma unroll
    for (int ni = 0; ni < 4; ni++) acc[mi][ni] = (f32x4){0.f, 0.f, 0.f, 0.f};

  for (int k0 = 0; k0 < K; k0 += 64) {
    __syncthreads();
#pragma unroll
    for (int i = 0; i < 4; i++) {
      int chunk = tid + i * 256;
      int r = chunk >> 3, c = (chunk & 7) << 3;
      *(bhalf8*)&As[r][c] = *(const bhalf8*)(A + (long)(row0 + r) * lda + k0 + c);
      *(bhalf8*)&Bs[r][c] = *(const bhalf8*)(Bt + (long)(col0 + r) * ldb + k0 + c);
    }
    __syncthreads();
#pragma unroll
    for (int kk = 0; kk < 2; kk++) {
      bhalf8 af[4], bf[4];
#pragma unroll
      for (int mi = 0; mi < 4; mi++)
        af[mi] = *(const bhalf8*)&As[wr * 64 + mi * 16 + lr][kk * 32 + lg * 8];
#pragma unroll
      for (int ni = 0; ni < 4; ni++)
        bf[ni] = *(const bhalf8*)&Bs[wc * 64 + ni * 16 + lr][kk * 32 + lg * 8];
#pragma unroll
      for (int mi = 0; mi < 4; mi++)
#pragma unroll
        for (int ni = 0; ni < 4; ni++)
          acc[mi][ni] = __builtin_amdgcn_mfma_f32_16x16x32_bf16(af[mi], bf[ni], acc[mi][ni], 0, 0, 0);
    }
  }

#pragma unroll
  for (int mi = 0; mi < 4; mi++) {
#pragma unroll
    for (int ni = 0; ni < 4; ni++) {
#pragma unroll
      for (int r = 0; r < 4; r++) {
        int row = row0 + wr * 64 + mi * 16 + lg * 4 + r;
        int col = col0 + wc * 64 + ni * 16 + lr;
        float v = acc[mi][ni][r];
        if (MODE == 0) {
          v = (v + bias[col]) * alpha;
          ((short*)Cp)[(long)b * c_bs + (long)row * ldc + col] = f2bf(v);
        } else if (MODE == 1) {
          v = (v + bias[row]) * alpha;
          ((short*)Cp)[(long)b * c_bs + (long)row * ldc + col] = f2bf(v);
        } else {
          v += bias[col];
          ((float*)Cp)[(long)b * c_bs + (long)row * ldc + col] = v;
        }
      }
    }
  }
}

// ---------------- flash attention, 8 waves / 256 q-rows per block ----------------
// grid: 256 blocks (16 q-tiles x 16 heads via XCD swizzle), 512 threads = 8 waves,
// __launch_bounds__(512,2): 1 block/CU, VGPR cap 256 (round-3's (512,4) spilled).
// Each wave owns 32 q rows; each lane owns ONE q row (q = l&31; lanes l, l+32 pair).
// LDS swizzle: 16-slot XOR key (row&15)<<4 -> all frag reads 2-way (free).
// V^T tile folded [64][256B]: dv rows r and r+64 share an LDS row (byte halves 0/128).
__global__ __launch_bounds__(512, 2) void k_attn(const short* __restrict__ q,
                                                 const short* __restrict__ k,
                                                 const short* __restrict__ vT,
                                                 short* __restrict__ cat) {
  __shared__ __align__(16) char smem[65536]; // 2 x (K 16KB + V^T 16KB)
  const int wg = blockIdx.x;
  const int wgid = (wg & 7) * 32 + (wg >> 3);   // XCD swizzle: 2 heads per XCD
  const int h = wgid >> 4;
  const int q0 = (wgid & 15) << 8;
  const int tid = threadIdx.x;
  const int wave = tid >> 6;                    // 0..7
  const int l31 = tid & 31;
  const int hi = (tid >> 5) & 1;
  const int swl = (tid & 15) << 4;              // XOR key for this lane's frag rows

  const long qk_base = (long)h * S_SEQ * DHEAD;
  const long vt_base = (long)h * DHEAD * S_SEQ;

  // ---- stage Q tile (256 rows x 256B = 64KB = full smem), swizzled ----
  {
    u32x4 qst[8];
#pragma unroll
    for (int r = 0; r < 8; r++) {
      int o = r * 8192 + tid * 16;
      int row = o >> 8, col = o & 255;
      qst[r] = *(const u32x4*)(q + qk_base + (long)(q0 + row) * DHEAD + (col >> 1));
    }
#pragma unroll
    for (int r = 0; r < 8; r++) {
      int o = r * 8192 + tid * 16;
      int row = o >> 8, col = o & 255;
      *(u32x4*)(smem + row * 256 + (col ^ ((row & 15) << 4))) = qst[r];
    }
  }
  __syncthreads();
  bhalf8 qf[8]; // B-frag: Q[q=l31][dk = kc*16 + hi*8 + j]
#pragma unroll
  for (int kc = 0; kc < 8; kc++) {
    int row = wave * 32 + l31;
    qf[kc] = *(const bhalf8*)(smem + row * 256 + ((kc * 32 + hi * 16) ^ swl));
  }
  __syncthreads(); // all waves done reading Q before K/V overwrites smem

  f32x16 accO[4];
#pragma unroll
  for (int d = 0; d < 4; d++)
#pragma unroll
    for (int r = 0; r < 16; r++) accO[d][r] = 0.f;
  float m_run = -1e30f, l_part = 0.f;

  u32x4 st[4];
  // staging (512 thr): K tile 16KB (64 rows x 256B), V^T folded 16KB (64 rows x 256B)
  auto load_tile = [&](int kv0) {
#pragma unroll
    for (int r2 = 0; r2 < 2; r2++) {
      int o = r2 * 8192 + tid * 16;
      int row = o >> 8, col = o & 255;
      st[r2] = *(const u32x4*)(k + qk_base + (long)(kv0 + row) * DHEAD + (col >> 1));
    }
#pragma unroll
    for (int r2 = 0; r2 < 2; r2++) {
      int o = r2 * 8192 + tid * 16;
      int dv = o >> 7, col = o & 127;
      st[2 + r2] = *(const u32x4*)(vT + vt_base + (long)dv * S_SEQ + kv0 + (col >> 1));
    }
  };
  auto write_tile = [&](char* buf) {
#pragma unroll
    for (int r2 = 0; r2 < 2; r2++) {
      int o = r2 * 8192 + tid * 16;
      int row = o >> 8, col = o & 255;
      *(u32x4*)(buf + row * 256 + (col ^ ((row & 15) << 4))) = st[r2];
    }
#pragma unroll
    for (int r2 = 0; r2 < 2; r2++) {
      int o = r2 * 8192 + tid * 16;
      int dv = o >> 7, col = o & 127;
      // folded: LDS row = dv&63, byte-half = (dv>>6)*128, key (dv&15)<<4
      *(u32x4*)(buf + 16384 + (dv & 63) * 256 +
                ((((dv >> 6) << 7) + col) ^ ((dv & 15) << 4))) = st[2 + r2];
    }
  };

  load_tile(0);
  write_tile(smem);
  load_tile(64);
  __syncthreads();

  const int NT = S_SEQ / 64;
  for (int t = 0; t < NT; t++) {
    char* buf = smem + (t & 1) * 32768;

    // ---- QK^T: S^T[kv][q], kv in regs, q = lane ----
    f32x16 accS[2];
#pragma unroll
    for (int kvb = 0; kvb < 2; kvb++)
#pragma unroll
      for (int r = 0; r < 16; r++) accS[kvb][r] = 0.f;

    __builtin_amdgcn_s_setprio(1);
#pragma unroll
    for (int kvb = 0; kvb < 2; kvb++) {
      int row = kvb * 32 + l31;
#pragma unroll
      for (int kc = 0; kc < 8; kc++) {
        bhalf8 kf = *(const bhalf8*)(buf + row * 256 + ((kc * 32 + hi * 16) ^ swl));
        accS[kvb] = __builtin_amdgcn_mfma_f32_32x32x16_bf16(kf, qf[kc], accS[kvb], 0, 0, 0);
      }
    }
    __builtin_amdgcn_s_setprio(0);

    // ---- online softmax (per-lane row; pair lane l^32 holds the other 32 kv) ----
    float mx[8];
#pragma unroll
    for (int g = 0; g < 8; g++) {
      const int kvb = g >> 2, b4 = (g & 3) * 4;
      mx[g] = fmaxf(fmaxf(accS[kvb][b4], accS[kvb][b4 + 1]),
                    fmaxf(accS[kvb][b4 + 2], accS[kvb][b4 + 3]));
    }
    float mc = fmaxf(fmaxf(fmaxf(mx[0], mx[1]), fmaxf(mx[2], mx[3])),
                     fmaxf(fmaxf(mx[4], mx[5]), fmaxf(mx[6], mx[7])));
    mc = fmaxf(mc, __shfl_xor(mc, 32));

    if (!__all(mc <= m_run + 8.f)) {   // defer-max: rescale only on real growth
      float mn = fmaxf(m_run, mc);
      float corr = __builtin_amdgcn_exp2f(m_run - mn);
      m_run = mn;
      l_part *= corr;
#pragma unroll
      for (int d = 0; d < 4; d++)
#pragma unroll
        for (int r = 0; r < 16; r++) accO[d][r] *= corr;
    }

    unsigned pk[2][4][2];
#pragma unroll
    for (int kvb = 0; kvb < 2; kvb++)
#pragma unroll
      for (int g = 0; g < 4; g++) {
        float p0 = __builtin_amdgcn_exp2f(accS[kvb][4 * g + 0] - m_run);
        float p1 = __builtin_amdgcn_exp2f(accS[kvb][4 * g + 1] - m_run);
        float p2 = __builtin_amdgcn_exp2f(accS[kvb][4 * g + 2] - m_run);
        float p3 = __builtin_amdgcn_exp2f(accS[kvb][4 * g + 3] - m_run);
        l_part += (p0 + p1) + (p2 + p3);
        pk[kvb][g][0] = pk2(p0, p1);
        pk[kvb][g][1] = pk2(p2, p3);
      }

    // ---- assemble PV B-operand in registers (xor-32 half exchange) ----
    bhalf8 pa[4]; // chunk c: P[q=l31][kv = 16c + 8hi + j]
#pragma unroll
    for (int kvb = 0; kvb < 2; kvb++)
#pragma unroll
      for (int c1 = 0; c1 < 2; c1++) {
        unsigned a0 = pk[kvb][2 * c1][0],     a1 = pk[kvb][2 * c1][1];
        unsigned b0 = pk[kvb][2 * c1 + 1][0], b1 = pk[kvb][2 * c1 + 1][1];
        unsigned s0a = (unsigned)__shfl_xor((int)a0, 32);
        unsigned s1a = (unsigned)__shfl_xor((int)a1, 32);
        unsigned s0b = (unsigned)__shfl_xor((int)b0, 32);
        unsigned s1b = (unsigned)__shfl_xor((int)b1, 32);
        union { unsigned u[4]; bhalf8 v; } cvt;
        cvt.u[0] = hi ? s0b : a0;
        cvt.u[1] = hi ? s1b : a1;
        cvt.u[2] = hi ? b0 : s0a;
        cvt.u[3] = hi ? b1 : s1a;
        pa[kvb * 2 + c1] = cvt.v;
      }

    // ---- PV: O^T[dv][q] += V^T[dv][kv] . P^T[kv][q] ----
    __builtin_amdgcn_s_setprio(1);
#pragma unroll
    for (int d = 0; d < 4; d++) {
      int vrow = ((d & 1) << 5) + l31;          // dv & 63
      int vhalf = (d >> 1) << 7;                // (dv>>6)*128
#pragma unroll
      for (int c = 0; c < 4; c++) {
        bhalf8 vf = *(const bhalf8*)(buf + 16384 + vrow * 256 +
                                     ((vhalf + c * 32 + hi * 16) ^ swl));
        accO[d] = __builtin_amdgcn_mfma_f32_32x32x16_bf16(vf, pa[c], accO[d], 0, 0, 0);
      }
    }
    __builtin_amdgcn_s_setprio(0);

    if (t + 1 < NT) write_tile(smem + ((t + 1) & 1) * 32768); // compiler waits vmcnt
    __syncthreads();
    if (t + 2 < NT) load_tile((t + 2) * 64);                  // async issue, lands under next compute
  }

  // ---- epilogue ----
  float l_tot = l_part + __shfl_xor(l_part, 32);
  float inv = 1.f / l_tot;
  long rowbase = (long)(q0 + wave * 32 + l31) * DMODEL + h * DHEAD;
#pragma unroll
  for (int d = 0; d < 4; d++)
#pragma unroll
    for (int rg = 0; rg < 4; rg++) {
      bhalf4 ov;
#pragma unroll
      for (int i = 0; i < 4; i++) ov[i] = f2bf(accO[d][rg * 4 + i] * inv);
      *(bhalf4*)(cat + rowbase + d * 32 + rg * 8 + hi * 4) = ov;
    }
}

// ---------------- launch ----------------
extern "C" void kernel_launch(void* const* d_in, const int* in_sizes, int n_in,
                              void* d_out, int out_size, void* d_ws, size_t ws_size,
                              hipStream_t stream) {
  const float* x  = (const float*)d_in[0];
  const float* Wq = (const float*)d_in[1];
  const float* bq = (const float*)d_in[2];
  const float* Wk = (const float*)d_in[3];
  const float* bk = (const float*)d_in[4];
  const float* Wv = (const float*)d_in[5];
  const float* bv = (const float*)d_in[6];
  const float* Wo = (const float*)d_in[7];
  const float* bo = (const float*)d_in[8];
  float* out = (float*)d_out;

  short* x_bf   = (short*)d_ws;                        // [4096][2048]
  short* Wqt    = x_bf  + (long)S_SEQ * DMODEL;        // [16][128][2048]
  short* Wkt    = Wqt   + (long)NHEAD * DHEAD * DMODEL;
  short* Wvt    = Wkt   + (long)NHEAD * DHEAD * DMODEL;
  short* Wot    = Wvt   + (long)NHEAD * DHEAD * DMODEL; // [2048][2048]
  short* q_bf   = Wot   + (long)DMODEL * DMODEL;        // [16][4096][128]
  short* k_bf   = q_bf  + (long)NHEAD * S_SEQ * DHEAD;
  short* vT_bf  = k_bf  + (long)NHEAD * S_SEQ * DHEAD;  // [16][128][4096]
  short* cat_bf = vT_bf + (long)NHEAD * DHEAD * S_SEQ;  // [4096][2048]

  dim3 blk(256);

  k_convert<<<dim3((S_SEQ * DMODEL / 4 + 255) / 256), blk, 0, stream>>>(x, x_bf, S_SEQ * DMODEL / 4);

  k_transpose<<<dim3((DMODEL / 64) * (DHEAD / 64), NHEAD), blk, 0, stream>>>(Wq, Wqt, DMODEL, DHEAD);
  k_transpose<<<dim3((DMODEL / 64) * (DHEAD / 64), NHEAD), blk, 0, stream>>>(Wk, Wkt, DMODEL, DHEAD);
  k_transpose<<<dim3((DMODEL / 64) * (DHEAD / 64), NHEAD), blk, 0, stream>>>(Wv, Wvt, DMODEL, DHEAD);
  k_transpose<<<dim3((DMODEL / 64) * (DMODEL / 64), 1), blk, 0, stream>>>(Wo, Wot, DMODEL, DMODEL);

  // scale*log2(e) folded into q so softmax exp is a single v_exp_f32 (base-2)
  const float alpha_q = 0.08838834764831845f * 1.4426950408889634f;

  k_gemm<0><<<dim3(32, NHEAD), blk, 0, stream>>>(x_bf, DMODEL, 0L,
                                                 Wqt, DMODEL, (long)DHEAD * DMODEL,
                                                 q_bf, DHEAD, (long)S_SEQ * DHEAD,
                                                 bq, DHEAD, alpha_q, 32, 1, DMODEL);
  k_gemm<0><<<dim3(32, NHEAD), blk, 0, stream>>>(x_bf, DMODEL, 0L,
                                                 Wkt, DMODEL, (long)DHEAD * DMODEL,
                                                 k_bf, DHEAD, (long)S_SEQ * DHEAD,
                                                 bk, DHEAD, 1.0f, 32, 1, DMODEL);
  // vT[h] = Wv[h]^T @ x^T + bv[h] (bias per row) : [128][4096] per head
  k_gemm<1><<<dim3(32, NHEAD), blk, 0, stream>>>(Wvt, DMODEL, (long)DHEAD * DMODEL,
                                                 x_bf, DMODEL, 0L,
                                                 vT_bf, S_SEQ, (long)DHEAD * S_SEQ,
                                                 bv, DHEAD, 1.0f, 1, 32, DMODEL);

  k_attn<<<dim3(256), dim3(512), 0, stream>>>(q_bf, k_bf, vT_bf, cat_bf);

  // out = cat @ Wo + bo : [4096][2048] f32
  k_gemm<2><<<dim3(32 * 16, 1), blk, 0, stream>>>(cat_bf, DMODEL, 0L,
                                                  Wot, DMODEL, 0L,
                                                  out, DMODEL, 0L,
                                                  bo, 0, 1.0f, 32, 16, DMODEL);
}